// Round 6
// baseline (390.025 us; speedup 1.0000x reference)
//
#include <hip/hip_runtime.h>
#include <hip/hip_bf16.h>
#include <math.h>

typedef __hip_bfloat16 bf16;
typedef __attribute__((ext_vector_type(8))) short short8;
typedef __attribute__((ext_vector_type(4))) float floatx4;
typedef __attribute__((ext_vector_type(16))) float floatx16;

__device__ __forceinline__ void async_copy16(const void* gptr, void* lptr) {
  __builtin_amdgcn_global_load_lds(
      (const __attribute__((address_space(1))) unsigned int*)gptr,
      (__attribute__((address_space(3))) unsigned int*)lptr,
      16, 0, 0);
}

__device__ __forceinline__ unsigned int f2bf_bits(float x) {
  bf16 h = __float2bfloat16(x);
  return (unsigned int)*reinterpret_cast<unsigned short*>(&h);
}

__device__ __forceinline__ float bfbits2f(unsigned int u) {
  unsigned v = u << 16;
  return *reinterpret_cast<float*>(&v);
}

__device__ __forceinline__ floatx4 mfma16(short8 a, short8 b, floatx4 c) {
  return __builtin_amdgcn_mfma_f32_16x16x32_bf16(a, b, c, 0, 0, 0);
}

// flag = 1 -> fp32 inputs, 0 -> bf16 inputs.
__global__ void dtype_sniff(const unsigned int* __restrict__ u, int* __restrict__ flag) {
  __shared__ int cnt[256];
  const int tid = threadIdx.x;
  const unsigned v = u[tid * 16];
  const int e = (v >> 7) & 0xFF;
  cnt[tid] = (e >= 90 && e <= 140) ? 1 : 0;
  __syncthreads();
  for (int s = 128; s > 0; s >>= 1) {
    if (tid < s) cnt[tid] += cnt[tid + s];
    __syncthreads();
  }
  if (tid == 0) flag[0] = (cnt[0] >= 192) ? 0 : 1;
}

// One kernel converting all inputs to bf16 (fp32 src if *flag else bf16 copy).
__global__ void conv_all(const void* hs, const void* wq, const void* wk, const void* wv,
                         const void* wo, const void* bq, const void* bk, const void* bv,
                         bf16* hsb, bf16* wqb, bf16* wkb, bf16* wvb, bf16* wob, bf16* b3,
                         long nhs4, const int* __restrict__ flag) {
  const bool f = (*flag != 0);
  const long W4 = 1048576, KV4 = 262144;  // H*H/4, KV*H/4
  const long total = nhs4 + W4 + 2 * KV4 + W4 + 512 + 128 + 128;
  const long stride = (long)gridDim.x * blockDim.x;
  for (long i = (long)blockIdx.x * blockDim.x + threadIdx.x; i < total; i += stride) {
    const void* src;
    bf16* dst;
    long off, j = i;
    if (j < nhs4) { src = hs; dst = hsb; off = j; }
    else if ((j -= nhs4) < W4) { src = wq; dst = wqb; off = j; }
    else if ((j -= W4) < KV4) { src = wk; dst = wkb; off = j; }
    else if ((j -= KV4) < KV4) { src = wv; dst = wvb; off = j; }
    else if ((j -= KV4) < W4) { src = wo; dst = wob; off = j; }
    else if ((j -= W4) < 512) { src = bq; dst = b3; off = j; }
    else if ((j -= 512) < 128) { src = bk; dst = b3 + 2048; off = j; }
    else { j -= 128; src = bv; dst = b3 + 2560; off = j; }
    uint2 o;
    if (f) {
      float4 v = ((const float4*)src)[off];
      o.x = f2bf_bits(v.x) | (f2bf_bits(v.y) << 16);
      o.y = f2bf_bits(v.z) | (f2bf_bits(v.w) << 16);
    } else {
      o = ((const uint2*)src)[off];
    }
    ((uint2*)dst)[off] = o;
  }
}

// RoPE cos/sin table: tab[pos*64 + i] = {cos, sin} of pos*theta^(-i/64).
__global__ void rope_table(float2* __restrict__ tab, int S) {
  const int id = blockIdx.x * blockDim.x + threadIdx.x;
  if (id >= S * 64) return;
  const int pos = id >> 6, i = id & 63;
  const float freq = exp2f((float)i * -0.31143075889569023f);
  const float ang = (float)pos * freq;
  float s, c;
  __sincosf(ang, &s, &c);
  tab[id] = make_float2(c, s);
}

// Fused QKV GEMM (m97 structure).  Q->Qb [M,2048], K->Kb [M,512],
// V->Vt [B,4,128,S] transposed.  bias3 = bq|bk|bv.
__global__ __launch_bounds__(256) void qkv_gemm(const bf16* __restrict__ A,
                                                const bf16* __restrict__ wq,
                                                const bf16* __restrict__ wk,
                                                const bf16* __restrict__ wv,
                                                const bf16* __restrict__ bias3,
                                                bf16* __restrict__ Qb,
                                                bf16* __restrict__ Kb,
                                                bf16* __restrict__ Vt,
                                                int M, int K, int S) {
  __shared__ __align__(16) short lA[128 * 32];
  __shared__ __align__(16) short lB[128 * 32];
  const int tid = threadIdx.x;
  const int wave = tid >> 6;
  const int lane = tid & 63;
  const int lrow = lane & 15;
  const int quad = lane >> 4;
  const int m0 = blockIdx.y * 128;
  const int n0 = blockIdx.x * 128;
  const int wm = (wave & 1) * 64;
  const int wn = (wave >> 1) * 64;
  const int sr = tid >> 2;
  const int sc = (tid & 3) * 8;

  const bf16* Wr;
  int nloc;
  if (n0 < 2048) { Wr = wq; nloc = n0; }
  else if (n0 < 2560) { Wr = wk; nloc = n0 - 2048; }
  else { Wr = wv; nloc = n0 - 2560; }

  floatx4 acc[4][4] = {};
  for (int k0 = 0; k0 < K; k0 += 32) {
#pragma unroll
    for (int it = 0; it < 2; ++it) {
      async_copy16(A + (size_t)(m0 + it * 64 + sr) * K + k0 + sc,
                   &lA[it * 2048 + wave * 512]);
      async_copy16(Wr + (size_t)(nloc + it * 64 + sr) * K + k0 + sc,
                   &lB[it * 2048 + wave * 512]);
    }
    __syncthreads();
    short8 af[4], bf[4];
#pragma unroll
    for (int i = 0; i < 4; ++i)
      af[i] = *(const short8*)&lA[(wm + i * 16 + lrow) * 32 + quad * 8];
#pragma unroll
    for (int j = 0; j < 4; ++j)
      bf[j] = *(const short8*)&lB[(wn + j * 16 + lrow) * 32 + quad * 8];
#pragma unroll
    for (int i = 0; i < 4; ++i)
#pragma unroll
      for (int j = 0; j < 4; ++j)
        acc[i][j] = mfma16(af[i], bf[j], acc[i][j]);
    __syncthreads();
  }

#pragma unroll
  for (int j = 0; j < 4; ++j) {
    const int col = n0 + wn + j * 16 + lrow;
    const float bv = __bfloat162float(bias3[col]);
#pragma unroll
    for (int i = 0; i < 4; ++i) {
      const int row = m0 + wm + i * 16 + quad * 4;
      if (n0 < 2048) {
#pragma unroll
        for (int r = 0; r < 4; ++r)
          Qb[(size_t)(row + r) * 2048 + col] = __float2bfloat16(acc[i][j][r] + bv);
      } else if (n0 < 2560) {
#pragma unroll
        for (int r = 0; r < 4; ++r)
          Kb[(size_t)(row + r) * 512 + (col - 2048)] = __float2bfloat16(acc[i][j][r] + bv);
      } else {
        const int dcol = col - 2560;
        const int kvh = dcol >> 7, d = dcol & 127;
        const int bb = row / S, s = row % S;
        uint2 pk;
        pk.x = f2bf_bits(acc[i][j][0] + bv) | (f2bf_bits(acc[i][j][1] + bv) << 16);
        pk.y = f2bf_bits(acc[i][j][2] + bv) | (f2bf_bits(acc[i][j][3] + bv) << 16);
        *(uint2*)&Vt[((size_t)(bb * 4 + kvh) * 128 + d) * S + s] = pk;
      }
    }
  }
}

// O-proj GEMM: out fp32 if *flag else bf16.
__global__ __launch_bounds__(256) void gemm_o(const bf16* __restrict__ A,
                                              const bf16* __restrict__ W,
                                              void* __restrict__ C,
                                              int M, int N, int K,
                                              const int* __restrict__ flag) {
  __shared__ __align__(16) short lA[128 * 32];
  __shared__ __align__(16) short lB[128 * 32];
  const int tid = threadIdx.x;
  const int wave = tid >> 6;
  const int lane = tid & 63;
  const int lrow = lane & 15;
  const int quad = lane >> 4;
  const int m0 = blockIdx.y * 128;
  const int n0 = blockIdx.x * 128;
  const int wm = (wave & 1) * 64;
  const int wn = (wave >> 1) * 64;
  const int sr = tid >> 2;
  const int sc = (tid & 3) * 8;
  const bool of32 = (*flag != 0);

  floatx4 acc[4][4] = {};
  for (int k0 = 0; k0 < K; k0 += 32) {
#pragma unroll
    for (int it = 0; it < 2; ++it) {
      async_copy16(A + (size_t)(m0 + it * 64 + sr) * K + k0 + sc,
                   &lA[it * 2048 + wave * 512]);
      async_copy16(W + (size_t)(n0 + it * 64 + sr) * K + k0 + sc,
                   &lB[it * 2048 + wave * 512]);
    }
    __syncthreads();
    short8 af[4], bf[4];
#pragma unroll
    for (int i = 0; i < 4; ++i)
      af[i] = *(const short8*)&lA[(wm + i * 16 + lrow) * 32 + quad * 8];
#pragma unroll
    for (int j = 0; j < 4; ++j)
      bf[j] = *(const short8*)&lB[(wn + j * 16 + lrow) * 32 + quad * 8];
#pragma unroll
    for (int i = 0; i < 4; ++i)
#pragma unroll
      for (int j = 0; j < 4; ++j)
        acc[i][j] = mfma16(af[i], bf[j], acc[i][j]);
    __syncthreads();
  }

#pragma unroll
  for (int j = 0; j < 4; ++j) {
    const int col = n0 + wn + j * 16 + lrow;
#pragma unroll
    for (int i = 0; i < 4; ++i) {
      const int row = m0 + wm + i * 16 + quad * 4;
#pragma unroll
      for (int r = 0; r < 4; ++r) {
        const size_t idx = (size_t)(row + r) * N + col;
        if (of32) ((float*)C)[idx] = acc[i][j][r];
        else ((bf16*)C)[idx] = __float2bfloat16(acc[i][j][r]);
      }
    }
  }
}

// Vectorized in-place RoPE using precomputed table.
__global__ __launch_bounds__(256) void rope_kernel(bf16* __restrict__ Qb,
                                                   bf16* __restrict__ Kb,
                                                   const int* __restrict__ pos_ids,
                                                   const float2* __restrict__ tab) {
  const int token = blockIdx.x;
  const int tid = threadIdx.x;
  const int pos = pos_ids[token];
  const int hh = tid >> 4;
  const int i4 = (tid & 15) * 4;
  float cs[4], sn[4];
#pragma unroll
  for (int e = 0; e < 4; ++e) {
    const float2 t = tab[pos * 64 + i4 + e];
    cs[e] = t.x; sn[e] = t.y;
  }
  {
    bf16* qp = Qb + (size_t)token * 2048 + hh * 128 + i4;
    uint2 lo = *(uint2*)qp, hi = *(uint2*)(qp + 64);
    unsigned lol[4] = {lo.x & 0xffff, lo.x >> 16, lo.y & 0xffff, lo.y >> 16};
    unsigned hil[4] = {hi.x & 0xffff, hi.x >> 16, hi.y & 0xffff, hi.y >> 16};
    uint2 olo, ohi;
    unsigned t[4], u[4];
#pragma unroll
    for (int e = 0; e < 4; ++e) {
      const float l = bfbits2f(lol[e]), h = bfbits2f(hil[e]);
      t[e] = f2bf_bits(l * cs[e] - h * sn[e]);
      u[e] = f2bf_bits(h * cs[e] + l * sn[e]);
    }
    olo.x = t[0] | (t[1] << 16); olo.y = t[2] | (t[3] << 16);
    ohi.x = u[0] | (u[1] << 16); ohi.y = u[2] | (u[3] << 16);
    *(uint2*)qp = olo;
    *(uint2*)(qp + 64) = ohi;
  }
  if (hh < 4) {
    bf16* kp = Kb + (size_t)token * 512 + hh * 128 + i4;
    uint2 lo = *(uint2*)kp, hi = *(uint2*)(kp + 64);
    unsigned lol[4] = {lo.x & 0xffff, lo.x >> 16, lo.y & 0xffff, lo.y >> 16};
    unsigned hil[4] = {hi.x & 0xffff, hi.x >> 16, hi.y & 0xffff, hi.y >> 16};
    uint2 olo, ohi;
    unsigned t[4], u[4];
#pragma unroll
    for (int e = 0; e < 4; ++e) {
      const float l = bfbits2f(lol[e]), h = bfbits2f(hil[e]);
      t[e] = f2bf_bits(l * cs[e] - h * sn[e]);
      u[e] = f2bf_bits(h * cs[e] + l * sn[e]);
    }
    olo.x = t[0] | (t[1] << 16); olo.y = t[2] | (t[3] << 16);
    ohi.x = u[0] | (u[1] << 16); ohi.y = u[2] | (u[3] << 16);
    *(uint2*)kp = olo;
    *(uint2*)(kp + 64) = ohi;
  }
}

// Flash attention, 32x32x16 MFMA, S^T/O^T orientation.  48 KB LDS -> 3 blocks/CU.
// K double-buffered (full-body in-flight window); V single-buffered, staged late
// between a raw lgkm-only barrier (keeps K DMA in flight) and __syncthreads.
// P exits QK^T in C-layout and is converted to PV's B-operand layout via a
// packed cross-half register exchange (no LDS round trip).
__global__ __launch_bounds__(256, 3) void flash_attn(const bf16* Q,
                                                     const bf16* __restrict__ K,
                                                     const bf16* __restrict__ Vt,
                                                     bf16* O, int S) {
  __shared__ __align__(16) short lK[2][16 * 512];  // 32 KB
  __shared__ __align__(16) short lV[16 * 512];     // 16 KB

  const int tid = threadIdx.x;
  const int wave = tid >> 6;
  const int lane = tid & 63;
  const int l31 = lane & 31;
  const int half = lane >> 5;
  const int bh = blockIdx.x;
  const int y = blockIdx.y;
  const int qt = (y < 8) ? y : 23 - y;  // pairs (qt,15-qt) co-resident per CU
  const int q0 = qt * 128;
  const int b = bh >> 4;
  const int h = bh & 15;
  const int kvh = h >> 2;
  const int wq0 = wave * 32;
  const int q_g = q0 + wq0 + l31;

  // Q fragments (B-operand): qf[ks] = Q[q_g][d = ks*16 + half*8 + j]
  short8 qf[8];
  {
    const bf16* qbase = Q + ((size_t)(b * S + q_g) * 16 + h) * 128 + half * 8;
#pragma unroll
    for (int ks = 0; ks < 8; ++ks)
      qf[ks] = *(const short8*)(qbase + ks * 16);
  }

  floatx16 acc[4] = {};
  float m_i = -1.0e30f, l_i = 0.0f;
  const float KEXP = 0.08838834764831845f * 1.44269504f;  // scale * log2(e)
  const int fk0 = wave * 4;
  const int niter = 2 * qt + 2;

  auto stageK = [&](int buf, int kv0) {
#pragma unroll
    for (int i = 0; i < 4; ++i) {
      const int fk = fk0 + i;
      const int mt = fk & 1, kstep = fk >> 1;
      async_copy16(K + ((size_t)(b * S + kv0 + mt * 32 + l31) * 4 + kvh) * 128 + kstep * 16 + half * 8,
                   &lK[buf][fk * 512]);
    }
  };
  auto stageV = [&](int kv0) {
#pragma unroll
    for (int i = 0; i < 4; ++i) {
      const int fk = fk0 + i;
      const int kvs = fk >> 2, mtd = fk & 3;
      async_copy16(Vt + ((size_t)(b * 4 + kvh) * 128 + mtd * 32 + l31) * S + kv0 + kvs * 16 + half * 8,
                   &lV[fk * 512]);
    }
  };

  stageK(0, 0);
  stageV(0);
  __syncthreads();  // publish K(0), V(0)

  for (int it = 0; it < niter; ++it) {
    const int kv0 = it * 64;
    const int cur = it & 1;
    if (it + 1 < niter) stageK(cur ^ 1, kv0 + 64);  // in flight through body

    // S^T = K·Q^T  (C: col=q=l31, row kv = mt*32 + (r&3)+8*(r>>2)+4*half)
    floatx16 st[2] = {};
#pragma unroll
    for (int ks = 0; ks < 8; ++ks) {
      short8 k0 = *(const short8*)&lK[cur][(ks * 2 + 0) * 512 + lane * 8];
      short8 k1 = *(const short8*)&lK[cur][(ks * 2 + 1) * 512 + lane * 8];
      st[0] = __builtin_amdgcn_mfma_f32_32x32x16_bf16(k0, qf[ks], st[0], 0, 0, 0);
      st[1] = __builtin_amdgcn_mfma_f32_32x32x16_bf16(k1, qf[ks], st[1], 0, 0, 0);
    }

    // causal mask (raw score domain) + per-lane online softmax
    float mx = -1.0e30f;
    if (kv0 + 63 > q0 + wq0) {
#pragma unroll
      for (int r = 0; r < 16; ++r) {
        const int kv_l = kv0 + (r & 3) + 8 * (r >> 2) + 4 * half;
        float v0 = st[0][r];
        v0 = (kv_l > q_g) ? -1.0e30f : v0;
        float v1 = st[1][r];
        v1 = (kv_l + 32 > q_g) ? -1.0e30f : v1;
        st[0][r] = v0; st[1][r] = v1;
        mx = fmaxf(mx, fmaxf(v0, v1));
      }
    } else {
#pragma unroll
      for (int r = 0; r < 16; ++r)
        mx = fmaxf(mx, fmaxf(st[0][r], st[1][r]));
    }
    mx = fmaxf(mx, __shfl_xor(mx, 32));
    const float mnew = fmaxf(m_i, mx);
    const float alpha = exp2f((m_i - mnew) * KEXP);
    m_i = mnew;
    float rs0 = 0.f, rs1 = 0.f, rs2 = 0.f, rs3 = 0.f;
#pragma unroll
    for (int r = 0; r < 16; r += 4) {
      float p00 = exp2f((st[0][r] - mnew) * KEXP);
      float p01 = exp2f((st[0][r + 1] - mnew) * KEXP);
      float p02 = exp2f((st[0][r + 2] - mnew) * KEXP);
      float p03 = exp2f((st[0][r + 3] - mnew) * KEXP);
      float p10 = exp2f((st[1][r] - mnew) * KEXP);
      float p11 = exp2f((st[1][r + 1] - mnew) * KEXP);
      float p12 = exp2f((st[1][r + 2] - mnew) * KEXP);
      float p13 = exp2f((st[1][r + 3] - mnew) * KEXP);
      st[0][r] = p00; st[0][r + 1] = p01; st[0][r + 2] = p02; st[0][r + 3] = p03;
      st[1][r] = p10; st[1][r + 1] = p11; st[1][r + 2] = p12; st[1][r + 3] = p13;
      rs0 += p00 + p10; rs1 += p01 + p11; rs2 += p02 + p12; rs3 += p03 + p13;
    }
    float rs = (rs0 + rs1) + (rs2 + rs3);
    rs += __shfl_xor(rs, 32);
    l_i = l_i * alpha + rs;
#pragma unroll
    for (int t = 0; t < 4; ++t)
#pragma unroll
      for (int r = 0; r < 16; ++r) acc[t][r] *= alpha;

    // PV: P^T as B-operand via packed cross-half exchange.
    // Group (t,m): regs 8m..8m+7 of st[t]; P0..P3 = bf16x2-packed pairs.
    // half=0 frag (k=kv16+0..7)  = [P0, P1, partnerP0, partnerP1]
    // half=1 frag (k=kv16+8..15) = [partnerP2, partnerP3, P2, P3]
#pragma unroll
    for (int kvs = 0; kvs < 4; ++kvs) {
      const int t = kvs >> 1, m = kvs & 1;
      const unsigned P0 = f2bf_bits(st[t][8 * m + 0]) | (f2bf_bits(st[t][8 * m + 1]) << 16);
      const unsigned P1 = f2bf_bits(st[t][8 * m + 2]) | (f2bf_bits(st[t][8 * m + 3]) << 16);
      const unsigned P2 = f2bf_bits(st[t][8 * m + 4]) | (f2bf_bits(st[t][8 * m + 5]) << 16);
      const unsigned P3 = f2bf_bits(st[t][8 * m + 6]) | (f2bf_bits(st[t][8 * m + 7]) << 16);
      const unsigned pP0 = __shfl_xor((int)P0, 32);
      const unsigned pP1 = __shfl_xor((int)P1, 32);
      const unsigned pP2 = __shfl_xor((int)P2, 32);
      const unsigned pP3 = __shfl_xor((int)P3, 32);
      union { short8 s; uint4 u; } pf;
      if (half == 0) { pf.u.x = P0; pf.u.y = P1; pf.u.z = pP0; pf.u.w = pP1; }
      else { pf.u.x = pP2; pf.u.y = pP3; pf.u.z = P2; pf.u.w = P3; }
#pragma unroll
      for (int mtd = 0; mtd < 4; ++mtd) {
        short8 vf = *(const short8*)&lV[(kvs * 4 + mtd) * 512 + lane * 8];
        acc[mtd] = __builtin_amdgcn_mfma_f32_32x32x16_bf16(vf, pf.s, acc[mtd], 0, 0, 0);
      }
    }

    // barrier A: all lV/lK[cur] reads done; K(i+1) DMA stays in flight.
    asm volatile("s_waitcnt lgkmcnt(0)\n\ts_barrier" ::: "memory");
    if (it + 1 < niter) stageV(kv0 + 64);
    __syncthreads();  // drains vmcnt: publishes K(i+1) and V(i+1)
  }

  const float inv_l = 1.0f / l_i;
  bf16* obase = O + ((size_t)(b * S + q_g) * 16 + h) * 128;
#pragma unroll
  for (int mtd = 0; mtd < 4; ++mtd)
#pragma unroll
    for (int g = 0; g < 4; ++g) {
      uint2 pk;
      pk.x = f2bf_bits(acc[mtd][4 * g] * inv_l) | (f2bf_bits(acc[mtd][4 * g + 1] * inv_l) << 16);
      pk.y = f2bf_bits(acc[mtd][4 * g + 2] * inv_l) | (f2bf_bits(acc[mtd][4 * g + 3] * inv_l) << 16);
      *(uint2*)(obase + mtd * 32 + 8 * g + 4 * half) = pk;
    }
}

extern "C" void kernel_launch(void* const* d_in, const int* in_sizes, int n_in,
                              void* d_out, int out_size, void* d_ws, size_t ws_size,
                              hipStream_t stream) {
  const void* hs = d_in[0];
  const void* wq = d_in[1];
  const void* bq = d_in[2];
  const void* wk = d_in[3];
  const void* bk = d_in[4];
  const void* wv = d_in[5];
  const void* bv = d_in[6];
  const void* wo = d_in[7];
  const int* pos = (const int*)d_in[8];

  const int S = 2048, H = 2048, KV = 512;
  const int B = in_sizes[0] / (S * H);
  const int M = B * S;

  char* ws = (char*)d_ws;
  size_t off = 0;
  auto alloc = [&](size_t bytes) { char* p = ws + off; off += (bytes + 255) & ~(size_t)255; return p; };
  bf16* hsb = (bf16*)alloc((size_t)M * H * 2);
  bf16* wqb = (bf16*)alloc((size_t)H * H * 2);
  bf16* wkb = (bf16*)alloc((size_t)KV * H * 2);
  bf16* wvb = (bf16*)alloc((size_t)KV * H * 2);
  bf16* wob = (bf16*)alloc((size_t)H * H * 2);
  bf16* bias3 = (bf16*)alloc(3072 * 2);
  bf16* Qb = (bf16*)alloc((size_t)M * H * 2);
  bf16* Kb = (bf16*)alloc((size_t)M * KV * 2);
  bf16* Vt = (bf16*)alloc((size_t)M * KV * 2);
  float2* tab = (float2*)alloc((size_t)S * 64 * sizeof(float2));
  int* flag = (int*)alloc(256);
  bf16* AO = Qb;  // flash writes O over its own Q rows (disjoint per block)

  dtype_sniff<<<1, 256, 0, stream>>>((const unsigned int*)hs, flag);
  conv_all<<<2048, 256, 0, stream>>>(hs, wq, wk, wv, wo, bq, bk, bv,
                                     hsb, wqb, wkb, wvb, wob, bias3,
                                     (long)M * H / 4, flag);
  rope_table<<<(S * 64 + 255) / 256, 256, 0, stream>>>(tab, S);
  qkv_gemm<<<dim3(24, M / 128), 256, 0, stream>>>(hsb, wqb, wkb, wvb, bias3,
                                                  Qb, Kb, Vt, M, H, S);
  rope_kernel<<<M, 256, 0, stream>>>(Qb, Kb, pos, tab);
  flash_attn<<<dim3(B * 16, S / 128), 256, 0, stream>>>(Qb, Kb, Vt, AO, S);
  gemm_o<<<dim3(H / 128, M / 128), 256, 0, stream>>>(AO, wob, d_out, M, H, H, flag);
}